// Round 13
// baseline (519.317 us; speedup 1.0000x reference)
//
#include <hip/hip_runtime.h>
#include <cstdint>
#include <cstddef>

typedef unsigned int u32;
typedef unsigned short u16;
typedef uint8_t u8;
typedef unsigned long long u64;

// Problem constants
constexpr int kNB = 2, kL = 3000, kS = 3000, kC = 256, kH = 256, kFC = 8, kD = 32;
constexpr int kTP = 3008;   // padded rows (47*64)
constexpr int kMW = 48;     // mask bit-words per row
constexpr int kNBLK = 512;  // persistent grid: 2 blocks/CU, co-resident
// 32^(-1/4) * sqrt(log2(e)): applied to BOTH q sides -> sim in log2 units, P = exp2(sim)
constexpr float kQSC = 0.5050097568f;

typedef __attribute__((ext_vector_type(8))) short short8;
typedef __attribute__((ext_vector_type(4))) float f32x4;

__device__ __forceinline__ u16 f2bf(float f) {          // RNE
  u32 u = __float_as_uint(f);
  u += 0x7FFFu + ((u >> 16) & 1u);
  return (u16)(u >> 16);
}
__device__ __forceinline__ float bf2f(u16 h) { return __uint_as_float(((u32)h) << 16); }
__device__ __forceinline__ f32x4 mfma16(short8 a, short8 b, f32x4 c) {
  return __builtin_amdgcn_mfma_f32_16x16x32_bf16(a, b, c, 0, 0, 0);
}
__device__ __forceinline__ u32 pk2(float a, float b) {   // truncate-pack two bf16
  return (__float_as_uint(a) >> 16) | (__float_as_uint(b) & 0xFFFF0000u);
}
__device__ __forceinline__ u32 bytes_nz(u32 w) {
  return ((w & 0xFFu) ? 1u : 0u) | (((w >> 8) & 0xFFu) ? 2u : 0u)
       | (((w >> 16) & 0xFFu) ? 4u : 0u) | ((w >> 24) ? 8u : 0u);
}
__device__ __forceinline__ u32 h2_nz(u32 w) {
  return ((w & 0xFFFFu) ? 1u : 0u) | ((w >> 16) ? 2u : 0u);
}

// ---------------- workspace layout (bytes) ----------------
constexpr size_t SZ_Q   = (size_t)kNB * kFC * kTP * kD * 2;  // 3,080,192
constexpr size_t SZ_MH  = (size_t)kNB * kTP * kH * 2;        // 3,080,192
constexpr size_t SZ_XB  = (size_t)kNB * kL * kC * 2;         // 3,072,000
constexpr size_t SZ_MKB = (size_t)kNB * kMW * kTP * 8;       // 2,310,144
constexpr size_t OFF_Q0 = 256;                               // ws[0..255] = barrier ctrs
constexpr size_t OFF_Q1 = OFF_Q0 + SZ_Q;
constexpr size_t OFF_V0 = OFF_Q1 + SZ_Q;
constexpr size_t OFF_V1 = OFF_V0 + SZ_Q;
constexpr size_t OFF_M0 = OFF_V1 + SZ_Q;
constexpr size_t OFF_M1 = OFF_M0 + SZ_MH;
constexpr size_t OFF_WT = OFF_M1 + SZ_MH;                    // WT_proj [512][256] bf16
constexpr size_t OFF_WM = OFF_WT + (size_t)2 * kH * kC * 2;  // WmT [256][256] bf16
constexpr size_t OFF_X0 = OFF_WM + (size_t)kC * kH * 2;      // xb0 bf16
constexpr size_t OFF_X1 = OFF_X0 + SZ_XB;
constexpr size_t OFF_MKB  = OFF_X1 + SZ_XB;                  // bits, word-major [n][48][3008]
constexpr size_t OFF_MKBT = OFF_MKB + SZ_MKB;

// ---- per-block dtype detection (deterministic) ----
__device__ __forceinline__ u32 detect_mf_block(const u8* __restrict__ mraw,
                                               int tid, int* cnt) {
  if (tid < 8) cnt[tid] = 0;
  __syncthreads();
  uint4 mv = ((const uint4*)mraw)[tid];
  u32 wds[4] = {mv.x, mv.y, mv.z, mv.w};
  int l1[4] = {0,0,0,0}; int l3f1 = 0, l3c = 0;
#pragma unroll
  for (int k = 0; k < 4; ++k) {
    u32 wv = wds[k];
#pragma unroll
    for (int j = 0; j < 4; ++j) {
      u32 b = (wv >> (8 * j)) & 0xFFu;
      l1[j] += (b == 1u);
      if (j == 1) l3f1 += (b == 0x3Fu);
      if (j & 1) l3c += (b == 0x3Cu);
    }
  }
  if (l1[0]) atomicAdd(&cnt[0], l1[0]);
  if (l1[1]) atomicAdd(&cnt[1], l1[1]);
  if (l1[2]) atomicAdd(&cnt[2], l1[2]);
  if (l1[3]) atomicAdd(&cnt[3], l1[3]);
  if (l3f1)  atomicAdd(&cnt[4], l3f1);
  if (l3c)   atomicAdd(&cnt[5], l3c);
  __syncthreads();
  u32 mf;
  if (cnt[1] + cnt[2] + cnt[3] > 64) mf = 0;
  else if (cnt[0] > 64)              mf = 2;
  else if (cnt[4] > 64)              mf = 1;
  else if (cnt[5] > 64)              mf = 4;
  else                               mf = 3;
  return mf;
}
__device__ __forceinline__ u32 detect_f2_block(const u8* __restrict__ xraw,
                                               int tid, int* cnt) {
  __syncthreads();
  if (tid == 0) cnt[6] = 0;
  __syncthreads();
  uint4 xv = ((const uint4*)xraw)[tid];
  u32 wds[4] = {xv.x, xv.y, xv.z, xv.w};
  int lex = 0;
#pragma unroll
  for (int k = 0; k < 4; ++k) {
    u32 b = (wds[k] >> 8) & 0x7Fu;
    lex += (b >= 0x3Eu && b <= 0x40u);
  }
  if (lex) atomicAdd(&cnt[6], lex);
  __syncthreads();
  return (cnt[6] > 300) ? 0u : 1u;
}

// ---- device-scope grid barrier (all kNBLK blocks co-resident) ----
__device__ __forceinline__ void gridbar(u32* bar, int idx, int tid) {
  __syncthreads();
  if (tid == 0) {
    __threadfence();                                   // release: agent-scope
    __hip_atomic_fetch_add(&bar[idx], 1u, __ATOMIC_ACQ_REL, __HIP_MEMORY_SCOPE_AGENT);
    while (__hip_atomic_load(&bar[idx], __ATOMIC_ACQUIRE, __HIP_MEMORY_SCOPE_AGENT)
           < (u32)kNBLK) { __builtin_amdgcn_s_sleep(2); }
    __threadfence();                                   // acquire side
  }
  __syncthreads();
}

constexpr int NB_MASK = 47 * 47 * 2;   // 4418
constexpr int NB_CVT  = 3000;
constexpr int NB_WT   = 2 * kH + kC;   // 768
constexpr int NB_PREP = NB_MASK + NB_CVT + NB_WT;  // 8186
constexpr int NB_PROJ = 94 * 8 * 2;    // 1504
constexpr int NB_FLSH = 47 * 16 * 2;   // 1504
constexpr int NB_MRG  = 94 * 4 * 2;    // 752

// ================= the persistent mega-kernel =================
__global__ __launch_bounds__(256, 2) void k_all(const void* __restrict__ mraw,
                                                const void* __restrict__ x0,
                                                const void* __restrict__ x1,
                                                const void* __restrict__ Wp,
                                                const void* __restrict__ Wm,
                                                const void* __restrict__ bp,
                                                const void* __restrict__ bm,
                                                u8* __restrict__ ws,
                                                void* __restrict__ out) {
  u32* bar  = (u32*)ws;
  u16* q0   = (u16*)(ws + OFF_Q0);
  u16* q1   = (u16*)(ws + OFF_Q1);
  u16* v0t  = (u16*)(ws + OFF_V0);
  u16* v1t  = (u16*)(ws + OFF_V1);
  u16* m0h  = (u16*)(ws + OFF_M0);
  u16* m1h  = (u16*)(ws + OFF_M1);
  u16* WT   = (u16*)(ws + OFF_WT);
  u16* WmT  = (u16*)(ws + OFF_WM);
  u16* xb0  = (u16*)(ws + OFF_X0);
  u16* xb1  = (u16*)(ws + OFF_X1);
  u64* mkb  = (u64*)(ws + OFF_MKB);
  u64* mkbt = (u64*)(ws + OFF_MKBT);

  const int bid = blockIdx.x, tid = threadIdx.x;
  const int w = tid >> 6, lane = tid & 63;
  const int quad = lane >> 4, c16 = lane & 15;

  __shared__ int dcnt[8];
  __align__(16) __shared__ u16 smem[4 * 4704];   // 37632 B, unioned across stages

  const u32 mf = detect_mf_block((const u8*)mraw, tid, dcnt);
  const u32 f2 = detect_f2_block((const u8*)x0, tid, dcnt);

  // =========== stage 1: prep (mask bits + x cvt + weight transposes) ===========
  for (int vb = bid; vb < NB_PREP; vb += kNBLK) {
    if (vb < NB_MASK) {
      const int n = vb / 2209, r2 = vb % 2209;
      const int l0 = (r2 / 47) * 64, s0 = (r2 % 47) * 64;
      u16 (*tb)[4] = (u16(*)[4])smem;
      {
        const int row = tid >> 2, sg = (tid & 3) * 16;
        const int l = l0 + row;
        u32 bits = 0;
        if (l < kL) {
          const size_t base = ((size_t)n * kL + l) * kS + s0 + sg;
          const bool full = (s0 + sg + 16 <= kS);
          if (mf == 3) {
            if (full) {
              const float4* p = (const float4*)(((const float*)mraw) + base);
              float4 a = p[0], b = p[1], c = p[2], d = p[3];
              bits = (u32)(a.x != 0.f)        | ((u32)(a.y != 0.f) << 1)
                   | ((u32)(a.z != 0.f) << 2) | ((u32)(a.w != 0.f) << 3)
                   | ((u32)(b.x != 0.f) << 4) | ((u32)(b.y != 0.f) << 5)
                   | ((u32)(b.z != 0.f) << 6) | ((u32)(b.w != 0.f) << 7)
                   | ((u32)(c.x != 0.f) << 8) | ((u32)(c.y != 0.f) << 9)
                   | ((u32)(c.z != 0.f) << 10)| ((u32)(c.w != 0.f) << 11)
                   | ((u32)(d.x != 0.f) << 12)| ((u32)(d.y != 0.f) << 13)
                   | ((u32)(d.z != 0.f) << 14)| ((u32)(d.w != 0.f) << 15);
            } else {
              for (int i = 0; i < 16; ++i)
                if (s0 + sg + i < kS && ((const float*)mraw)[base + i] != 0.f) bits |= 1u << i;
            }
          } else if (mf == 2) {
            if (full) {
              const uint4* p = (const uint4*)(((const u32*)mraw) + base);
              uint4 a = p[0], b = p[1], c = p[2], d = p[3];
              bits = (u32)(a.x != 0)        | ((u32)(a.y != 0) << 1)
                   | ((u32)(a.z != 0) << 2) | ((u32)(a.w != 0) << 3)
                   | ((u32)(b.x != 0) << 4) | ((u32)(b.y != 0) << 5)
                   | ((u32)(b.z != 0) << 6) | ((u32)(b.w != 0) << 7)
                   | ((u32)(c.x != 0) << 8) | ((u32)(c.y != 0) << 9)
                   | ((u32)(c.z != 0) << 10)| ((u32)(c.w != 0) << 11)
                   | ((u32)(d.x != 0) << 12)| ((u32)(d.y != 0) << 13)
                   | ((u32)(d.z != 0) << 14)| ((u32)(d.w != 0) << 15);
            } else {
              for (int i = 0; i < 16; ++i)
                if (s0 + sg + i < kS && ((const u32*)mraw)[base + i]) bits |= 1u << i;
            }
          } else if (mf == 0) {
            if (full) {
              const u8* m8 = (const u8*)mraw + base;
              uint2 a = *(const uint2*)(m8);
              uint2 b = *(const uint2*)(m8 + 8);
              bits = bytes_nz(a.x) | (bytes_nz(a.y) << 4)
                   | (bytes_nz(b.x) << 8) | (bytes_nz(b.y) << 12);
            } else {
              for (int i = 0; i < 16; ++i)
                if (s0 + sg + i < kS && ((const u8*)mraw)[base + i]) bits |= 1u << i;
            }
          } else {
            if (full) {
              const u16* m16 = (const u16*)mraw + base;
              uint4 a = *(const uint4*)(m16);
              uint4 b = *(const uint4*)(m16 + 8);
              bits = h2_nz(a.x) | (h2_nz(a.y) << 2) | (h2_nz(a.z) << 4) | (h2_nz(a.w) << 6)
                   | (h2_nz(b.x) << 8) | (h2_nz(b.y) << 10)
                   | (h2_nz(b.z) << 12) | (h2_nz(b.w) << 14);
            } else {
              for (int i = 0; i < 16; ++i)
                if (s0 + sg + i < kS && ((const u16*)mraw)[base + i]) bits |= 1u << i;
            }
          }
        }
        tb[row][tid & 3] = (u16)bits;
      }
      __syncthreads();
      for (int k = 0; k < 16; ++k) {
        const int ro = w * 16 + k;
        u32 b1 = (tb[ro][lane >> 4] >> (lane & 15)) & 1;
        u64 word = __ballot((int)b1);
        if (lane == 0) mkb[((size_t)n * kMW + (s0 >> 6)) * kTP + l0 + ro] = word;
        u32 b2 = (tb[lane][ro >> 4] >> (ro & 15)) & 1;
        u64 wordt = __ballot((int)b2);
        if (lane == 0) mkbt[((size_t)n * kMW + (l0 >> 6)) * kTP + s0 + ro] = wordt;
      }
      __syncthreads();
    } else if (vb < NB_MASK + NB_CVT) {
      const int b2 = vb - NB_MASK;
      const void* X = (b2 >= 1500) ? x1 : x0;
      u16* B = (b2 >= 1500) ? xb1 : xb0;
      const int i = (b2 % 1500) * 256 + tid;
      if (f2 == 0) {
        ((uint2*)B)[i] = ((const uint2*)X)[i];
      } else {
        float4 v = ((const float4*)X)[i];
        uint2 o;
        o.x = (u32)f2bf(v.x) | ((u32)f2bf(v.y) << 16);
        o.y = (u32)f2bf(v.z) | ((u32)f2bf(v.w) << 16);
        ((uint2*)B)[i] = o;
      }
    } else {
      const int b = vb - NB_MASK - NB_CVT, k = tid;
      if (b < 2 * kH) {
        int col = b;
        u16 v = (f2 == 0) ? ((const u16*)Wp)[(size_t)k * (2 * kH) + col]
                          : f2bf(((const float*)Wp)[(size_t)k * (2 * kH) + col]);
        WT[(size_t)col * kC + k] = v;
      } else {
        int col = b - 2 * kH;
        u16 v = (f2 == 0) ? ((const u16*)Wm)[(size_t)k * kC + col]
                          : f2bf(((const float*)Wm)[(size_t)k * kC + col]);
        WmT[(size_t)col * kH + k] = v;
      }
    }
  }
  gridbar(bar, 0, tid);

  // =========== stage 2: projection GEMM (64x64 tiles, LDS-staged B) ===========
  for (int vb = bid; vb < NB_PROJ; vb += kNBLK) {
    const int rb = vb % 94, cb = (vb / 94) % 8, z = vb / 752;
    const u16* X = z ? xb1 : xb0;
    u16* Q = z ? q1 : q0;
    u16* V = z ? v1t : v0t;
    u16* sB = smem;
    {
      const u16* wp = WT + (size_t)(cb * 64 + (tid >> 2)) * kC + (tid & 3) * 64;
      u16* sp = sB + (tid >> 2) * 264 + (tid & 3) * 64;
#pragma unroll
      for (int i = 0; i < 8; ++i) *(uint4*)(sp + i * 8) = *(const uint4*)(wp + i * 8);
    }
    __syncthreads();

    const int arow = rb * 64 + w * 16 + c16;
    const u16* ap = X + (size_t)arow * kC + quad * 8;
    f32x4 acc[4];
#pragma unroll
    for (int cg = 0; cg < 4; ++cg) acc[cg] = f32x4{0.f,0.f,0.f,0.f};
#pragma unroll
    for (int k0 = 0; k0 < 8; ++k0) {
      short8 a = *(const short8*)(ap + k0 * 32);
#pragma unroll
      for (int cg = 0; cg < 4; ++cg) {
        short8 b = *(const short8*)(sB + (cg * 16 + c16) * 264 + k0 * 32 + quad * 8);
        acc[cg] = mfma16(a, b, acc[cg]);
      }
    }

    const int row0 = rb * 64 + w * 16 + quad * 4;
    if (row0 < 2 * kL) {
      const int n = (row0 >= kL) ? 1 : 0;
      const int t0 = row0 - n * kL;
#pragma unroll
      for (int cg = 0; cg < 4; ++cg) {
        const int c = cb * 64 + cg * 16 + c16;
        float bb = (f2 == 0) ? bf2f(((const u16*)bp)[c]) : ((const float*)bp)[c];
        if (c < kH) {
          int ff = c >> 5, d = c & 31;
          u16* qp = Q + ((size_t)(n * kFC + ff) * kTP + t0) * kD + d;
#pragma unroll
          for (int r = 0; r < 4; ++r) qp[(size_t)r * kD] = f2bf((acc[cg][r] + bb) * kQSC);
        } else {
          int cc = c - kH;
          int ff = cc >> 5, d = cc & 31;
          uint2 o;
          o.x = (u32)f2bf(acc[cg][0] + bb) | ((u32)f2bf(acc[cg][1] + bb) << 16);
          o.y = (u32)f2bf(acc[cg][2] + bb) | ((u32)f2bf(acc[cg][3] + bb) << 16);
          *(uint2*)(V + ((size_t)(n * kFC + ff) * kD + d) * kTP + t0) = o;
        }
      }
    }
    __syncthreads();
  }
  gridbar(bar, 1, tid);

  // =========== stage 3: flash attention (two-pass, ones-MFMA row sums) ===========
  for (int vb = bid; vb < NB_FLSH; vb += kNBLK) {
    const int bx = vb % 47, nf = (vb / 47) % 16, z = vb / 752;
    const u16* QA = z ? q1 : q0;
    const u16* QB = z ? q0 : q1;
    const u16* VT = z ? v0t : v1t;
    const u64* MB = z ? mkbt : mkb;
    u16* MO = z ? m1h : m0h;
    const int n = nf >> 3, f = nf & 7;

    u16* sP = smem + w * 4704;
    const u16* qa = QA + (size_t)(n * kFC + f) * kTP * kD;
    const u16* qb = QB + (size_t)(n * kFC + f) * kTP * kD;
    const u16* vt = VT + (size_t)(n * kFC + f) * kD * kTP;
    const u64* mb = MB + (size_t)n * kMW * kTP;
    const int l0 = bx * 64;

    short8 af[4];
#pragma unroll
    for (int g = 0; g < 4; ++g) {
      const int ra = l0 + g * 16 + c16;
      af[g] = *(const short8*)(qa + (size_t)ra * kD + quad * 8);
    }
    short8 bones;
#pragma unroll
    for (int i = 0; i < 8; ++i) bones[i] = (short)0x3F80;

    f32x4 acc[4][2], accS[4];
#pragma unroll
    for (int g = 0; g < 4; ++g) {
      acc[g][0] = f32x4{0.f,0.f,0.f,0.f};
      acc[g][1] = f32x4{0.f,0.f,0.f,0.f};
      accS[g]   = f32x4{0.f,0.f,0.f,0.f};
    }

    u64 mword = mb[(size_t)w * kTP + l0 + lane];
    short8 aq0, aq1, aq2, aq3;
    {
      const u16* qbase = qb + (size_t)(w * 64 + c16) * kD + quad * 8;
      aq0 = *(const short8*)(qbase);
      aq1 = *(const short8*)(qbase + (size_t)16 * kD);
      aq2 = *(const short8*)(qbase + (size_t)32 * kD);
      aq3 = *(const short8*)(qbase + (size_t)48 * kD);
    }

#pragma unroll 1
    for (int jc = w; jc < 47; jc += 4) {
      const int j0 = jc * 64;
      const u16* vbp = vt + (size_t)c16 * kTP + j0 + quad * 8;
      short8 bv00 = *(const short8*)(vbp);
      short8 bv01 = *(const short8*)(vbp + (size_t)16 * kTP);
      short8 bv10 = *(const short8*)(vbp + 32);
      short8 bv11 = *(const short8*)(vbp + (size_t)16 * kTP + 32);

      const u32 mlo = (u32)mword, mhi = (u32)(mword >> 32);

#pragma unroll
      for (int g = 0; g < 4; ++g) {
        const u32 lo = (u32)__shfl((int)mlo, g * 16 + c16);
        const u32 hi = (u32)__shfl((int)mhi, g * 16 + c16);
#pragma unroll
        for (int t = 0; t < 4; ++t) {
          short8 aq = (t == 0) ? aq0 : (t == 1) ? aq1 : (t == 2) ? aq2 : aq3;
          f32x4 zz = {0.f,0.f,0.f,0.f};
          f32x4 s = mfma16(aq, af[g], zz);       // C[s=quad*4+r][l=c16]
          const u32 hh = (t & 2) ? hi : lo;
          const int base = (t & 1) * 16 + quad * 4;
          float p0 = ((hh >> (base + 0)) & 1) ? __builtin_amdgcn_exp2f(s[0]) : 0.f;
          float p1 = ((hh >> (base + 1)) & 1) ? __builtin_amdgcn_exp2f(s[1]) : 0.f;
          float p2 = ((hh >> (base + 2)) & 1) ? __builtin_amdgcn_exp2f(s[2]) : 0.f;
          float p3 = ((hh >> (base + 3)) & 1) ? __builtin_amdgcn_exp2f(s[3]) : 0.f;
          uint2 pw; pw.x = pk2(p0, p1); pw.y = pk2(p2, p3);
          *(uint2*)(sP + (g * 16 + c16) * 72 + t * 16 + quad * 4) = pw;
        }
      }

      {
        int jn = jc + 4;
        const int jl = (jn < 47) ? jn : w;
        mword = mb[(size_t)jl * kTP + l0 + lane];
        const u16* qn = qb + (size_t)(jl * 64 + c16) * kD + quad * 8;
        aq0 = *(const short8*)(qn);
        aq1 = *(const short8*)(qn + (size_t)16 * kD);
        aq2 = *(const short8*)(qn + (size_t)32 * kD);
        aq3 = *(const short8*)(qn + (size_t)48 * kD);
      }

#pragma unroll
      for (int g = 0; g < 4; ++g) {
        short8 ap0 = *(const short8*)(sP + (g * 16 + c16) * 72 + quad * 8);
        short8 ap1 = *(const short8*)(sP + (g * 16 + c16) * 72 + 32 + quad * 8);
        acc[g][0] = mfma16(ap0, bv00, acc[g][0]);
        acc[g][1] = mfma16(ap0, bv01, acc[g][1]);
        accS[g]   = mfma16(ap0, bones, accS[g]);
        acc[g][0] = mfma16(ap1, bv10, acc[g][0]);
        acc[g][1] = mfma16(ap1, bv11, acc[g][1]);
        accS[g]   = mfma16(ap1, bones, accS[g]);
      }
    }

    // cross-wave combine (accS already in C layout)
    __syncthreads();
    float* buf = (float*)smem;
    if (w > 0) {
      const int rbase = (w - 1) * 3072;
#pragma unroll
      for (int g = 0; g < 4; ++g) {
#pragma unroll
        for (int r = 0; r < 4; ++r) {
          buf[rbase + (g * 12 + r)     * 64 + lane] = acc[g][0][r];
          buf[rbase + (g * 12 + 4 + r) * 64 + lane] = acc[g][1][r];
          buf[rbase + (g * 12 + 8 + r) * 64 + lane] = accS[g][r];
        }
      }
    }
    __syncthreads();
    if (w == 0) {
#pragma unroll
      for (int g = 0; g < 4; ++g) {
#pragma unroll
        for (int r = 0; r < 4; ++r) {
          float n0 = acc[g][0][r], n1 = acc[g][1][r], ls = accS[g][r];
#pragma unroll
          for (int ww = 0; ww < 3; ++ww) {
            n0 += buf[ww * 3072 + (g * 12 + r)     * 64 + lane];
            n1 += buf[ww * 3072 + (g * 12 + 4 + r) * 64 + lane];
            ls += buf[ww * 3072 + (g * 12 + 8 + r) * 64 + lane];
          }
          float rd = (ls > 0.f) ? (1.f / ls) : 0.f;
          int lrow = l0 + g * 16 + quad * 4 + r;
          if (lrow < kL) {
            size_t basep = ((size_t)n * kTP + lrow) * kH + f * kD;
            MO[basep + c16]      = f2bf(n0 * rd);
            MO[basep + 16 + c16] = f2bf(n1 * rd);
          }
        }
      }
    }
    __syncthreads();
  }
  gridbar(bar, 2, tid);

  // =========== stage 4: merge GEMM + bias -> out ===========
  for (int vb = bid; vb < NB_MRG; vb += kNBLK) {
    const int rb = vb % 94, cb = (vb / 94) % 4, z = vb / 376;
    const u16* A = z ? m1h : m0h;
    u16* sB = smem;
    {
      const u16* wp = WmT + (size_t)(cb * 64 + (tid >> 2)) * kH + (tid & 3) * 64;
      u16* sp = sB + (tid >> 2) * 264 + (tid & 3) * 64;
#pragma unroll
      for (int i = 0; i < 8; ++i) *(uint4*)(sp + i * 8) = *(const uint4*)(wp + i * 8);
    }
    __syncthreads();

    const int arow = rb * 64 + w * 16 + c16;
    const u16* ap = A + (size_t)arow * kH + quad * 8;
    f32x4 acc[4];
#pragma unroll
    for (int cg = 0; cg < 4; ++cg) acc[cg] = f32x4{0.f,0.f,0.f,0.f};
#pragma unroll
    for (int k0 = 0; k0 < 8; ++k0) {
      short8 a = *(const short8*)(ap + k0 * 32);
#pragma unroll
      for (int cg = 0; cg < 4; ++cg) {
        short8 b = *(const short8*)(sB + (cg * 16 + c16) * 264 + k0 * 32 + quad * 8);
        acc[cg] = mfma16(a, b, acc[cg]);
      }
    }

    const int row0 = rb * 64 + w * 16 + quad * 4;
    const int n = (row0 >= kTP) ? 1 : 0;
    const int t0 = row0 - n * kTP;
    const size_t obase = (size_t)z * ((size_t)kNB * kL * kC);
#pragma unroll
    for (int cg = 0; cg < 4; ++cg) {
      const int c = cb * 64 + cg * 16 + c16;
      float bb = (f2 == 0) ? bf2f(((const u16*)bm)[c]) : ((const float*)bm)[c];
#pragma unroll
      for (int r = 0; r < 4; ++r) {
        const int t = t0 + r;
        if (t < kL) {
          size_t oi = obase + ((size_t)n * kL + t) * kC + c;
          float v = acc[cg][r] + bb;
          if (f2 == 0) ((u16*)out)[oi] = f2bf(v);
          else         ((float*)out)[oi] = v;
        }
      }
    }
    __syncthreads();
  }
}

// ---------------- host ----------------
extern "C" void kernel_launch(void* const* d_in, const int* in_sizes, int n_in,
                              void* d_out, int out_size, void* d_ws, size_t ws_size,
                              hipStream_t stream) {
  (void)in_sizes; (void)n_in; (void)out_size; (void)ws_size;
  const void* x0 = d_in[0];
  const void* x1 = d_in[1];
  const void* mraw = d_in[2];
  const void* Wp = d_in[3];
  const void* bp = d_in[4];
  const void* Wm = d_in[5];
  const void* bm = d_in[6];

  hipMemsetAsync(d_ws, 0, 256, stream);   // zero grid-barrier counters
  k_all<<<dim3(kNBLK), 256, 0, stream>>>(
      mraw, x0, x1, Wp, Wm, bp, bm, (u8*)d_ws, d_out);
}

// Round 14
// 252.336 us; speedup vs baseline: 2.0580x; 2.0580x over previous
//
#include <hip/hip_runtime.h>
#include <cstdint>
#include <cstddef>

typedef unsigned int u32;
typedef unsigned short u16;
typedef uint8_t u8;
typedef unsigned long long u64;

// Problem constants
constexpr int kNB = 2, kL = 3000, kS = 3000, kC = 256, kH = 256, kFC = 8, kD = 32;
constexpr int kTP = 3008;   // padded rows (47*64)
constexpr int kMW = 48;     // mask bit-words per row
// 32^(-1/4) * sqrt(log2(e)): applied to BOTH q sides -> sim in log2 units, P = exp2(sim)
constexpr float kQSC = 0.5050097568f;

typedef __attribute__((ext_vector_type(8))) short short8;
typedef __attribute__((ext_vector_type(4))) float f32x4;

__device__ __forceinline__ u16 f2bf(float f) {          // RNE
  u32 u = __float_as_uint(f);
  u += 0x7FFFu + ((u >> 16) & 1u);
  return (u16)(u >> 16);
}
__device__ __forceinline__ float bf2f(u16 h) { return __uint_as_float(((u32)h) << 16); }
__device__ __forceinline__ f32x4 mfma16(short8 a, short8 b, f32x4 c) {
  return __builtin_amdgcn_mfma_f32_16x16x32_bf16(a, b, c, 0, 0, 0);
}
__device__ __forceinline__ u32 pk2(float a, float b) {   // truncate-pack two bf16
  return (__float_as_uint(a) >> 16) | (__float_as_uint(b) & 0xFFFF0000u);
}
__device__ __forceinline__ u32 bytes_nz(u32 w) {
  return ((w & 0xFFu) ? 1u : 0u) | (((w >> 8) & 0xFFu) ? 2u : 0u)
       | (((w >> 16) & 0xFFu) ? 4u : 0u) | ((w >> 24) ? 8u : 0u);
}
__device__ __forceinline__ u32 h2_nz(u32 w) {
  return ((w & 0xFFFFu) ? 1u : 0u) | ((w >> 16) ? 2u : 0u);
}

// ---- per-block dtype detection (deterministic, graph-safe) ----
__device__ __forceinline__ u32 detect_mf_block(const u8* __restrict__ mraw,
                                               int tid, int* cnt) {
  if (tid < 8) cnt[tid] = 0;
  __syncthreads();
  uint4 mv = ((const uint4*)mraw)[tid];
  u32 wds[4] = {mv.x, mv.y, mv.z, mv.w};
  int l1[4] = {0,0,0,0}; int l3f1 = 0, l3c = 0;
#pragma unroll
  for (int k = 0; k < 4; ++k) {
    u32 wv = wds[k];
#pragma unroll
    for (int j = 0; j < 4; ++j) {
      u32 b = (wv >> (8 * j)) & 0xFFu;
      l1[j] += (b == 1u);
      if (j == 1) l3f1 += (b == 0x3Fu);
      if (j & 1) l3c += (b == 0x3Cu);
    }
  }
  if (l1[0]) atomicAdd(&cnt[0], l1[0]);
  if (l1[1]) atomicAdd(&cnt[1], l1[1]);
  if (l1[2]) atomicAdd(&cnt[2], l1[2]);
  if (l1[3]) atomicAdd(&cnt[3], l1[3]);
  if (l3f1)  atomicAdd(&cnt[4], l3f1);
  if (l3c)   atomicAdd(&cnt[5], l3c);
  __syncthreads();
  u32 mf;
  if (cnt[1] + cnt[2] + cnt[3] > 64) mf = 0;
  else if (cnt[0] > 64)              mf = 2;
  else if (cnt[4] > 64)              mf = 1;
  else if (cnt[5] > 64)              mf = 4;
  else                               mf = 3;
  return mf;
}
__device__ __forceinline__ u32 detect_f2_block(const u8* __restrict__ xraw,
                                               int tid, int* cnt) {
  if (tid == 0) cnt[0] = 0;
  __syncthreads();
  uint4 xv = ((const uint4*)xraw)[tid];
  u32 wds[4] = {xv.x, xv.y, xv.z, xv.w};
  int lex = 0;
#pragma unroll
  for (int k = 0; k < 4; ++k) {
    u32 b = (wds[k] >> 8) & 0x7Fu;
    lex += (b >= 0x3Eu && b <= 0x40u);
  }
  if (lex) atomicAdd(&cnt[0], lex);
  __syncthreads();
  return (cnt[0] > 300) ? 0u : 1u;
}

// ---------------- workspace layout (bytes) ----------------
constexpr size_t SZ_Q   = (size_t)kNB * kFC * kTP * kD * 2;
constexpr size_t SZ_MH  = (size_t)kNB * kTP * kH * 2;
constexpr size_t SZ_XB  = (size_t)kNB * kL * kC * 2;
constexpr size_t SZ_MKB = (size_t)kNB * kMW * kTP * 8;
constexpr size_t OFF_Q0 = 256;
constexpr size_t OFF_Q1 = OFF_Q0 + SZ_Q;
constexpr size_t OFF_V0 = OFF_Q1 + SZ_Q;
constexpr size_t OFF_V1 = OFF_V0 + SZ_Q;
constexpr size_t OFF_M0 = OFF_V1 + SZ_Q;
constexpr size_t OFF_M1 = OFF_M0 + SZ_MH;
constexpr size_t OFF_WT = OFF_M1 + SZ_MH;                    // WT_proj [512][256] bf16
constexpr size_t OFF_WM = OFF_WT + (size_t)2 * kH * kC * 2;  // WmT [256][256] bf16
constexpr size_t OFF_X0 = OFF_WM + (size_t)kC * kH * 2;      // xb0 bf16 (f32 input only)
constexpr size_t OFF_X1 = OFF_X0 + SZ_XB;
constexpr size_t OFF_MKB  = OFF_X1 + SZ_XB;                  // bits, word-major [n][48][3008]
constexpr size_t OFF_MKBT = OFF_MKB + SZ_MKB;

// ---------------- K1: prep = mask bits + (f32-only) x cast + weight transpose ------
constexpr int NB_MASK = 47 * 47 * 2;   // 4418
constexpr int NB_CVT  = 3000;
constexpr int NB_WT   = 2 * kH + kC;   // 768

__global__ __launch_bounds__(256) void k_prep(const void* __restrict__ mraw,
                                              const void* __restrict__ x0,
                                              const void* __restrict__ x1,
                                              const void* __restrict__ Wp,
                                              const void* __restrict__ Wm,
                                              u64* __restrict__ mkb, u64* __restrict__ mkbt,
                                              u16* __restrict__ xb0, u16* __restrict__ xb1,
                                              u16* __restrict__ WT, u16* __restrict__ WmT) {
  const int bx = blockIdx.x, tid = threadIdx.x;
  __shared__ int dcnt[8];
  if (bx < NB_MASK) {
    const u32 mf = detect_mf_block((const u8*)mraw, tid, dcnt);
    const int n = bx / 2209, r2 = bx % 2209;
    const int l0 = (r2 / 47) * 64, s0 = (r2 % 47) * 64;
    __shared__ u16 tb[64][4];
    {
      const int row = tid >> 2, sg = (tid & 3) * 16;
      const int l = l0 + row;
      u32 bits = 0;
      if (l < kL) {
        const size_t base = ((size_t)n * kL + l) * kS + s0 + sg;
        const bool full = (s0 + sg + 16 <= kS);
        if (mf == 3) {
          if (full) {
            const float4* p = (const float4*)(((const float*)mraw) + base);
            float4 a = p[0], b = p[1], c = p[2], d = p[3];
            bits = (u32)(a.x != 0.f)        | ((u32)(a.y != 0.f) << 1)
                 | ((u32)(a.z != 0.f) << 2) | ((u32)(a.w != 0.f) << 3)
                 | ((u32)(b.x != 0.f) << 4) | ((u32)(b.y != 0.f) << 5)
                 | ((u32)(b.z != 0.f) << 6) | ((u32)(b.w != 0.f) << 7)
                 | ((u32)(c.x != 0.f) << 8) | ((u32)(c.y != 0.f) << 9)
                 | ((u32)(c.z != 0.f) << 10)| ((u32)(c.w != 0.f) << 11)
                 | ((u32)(d.x != 0.f) << 12)| ((u32)(d.y != 0.f) << 13)
                 | ((u32)(d.z != 0.f) << 14)| ((u32)(d.w != 0.f) << 15);
          } else {
            for (int i = 0; i < 16; ++i)
              if (s0 + sg + i < kS && ((const float*)mraw)[base + i] != 0.f) bits |= 1u << i;
          }
        } else if (mf == 2) {
          if (full) {
            const uint4* p = (const uint4*)(((const u32*)mraw) + base);
            uint4 a = p[0], b = p[1], c = p[2], d = p[3];
            bits = (u32)(a.x != 0)        | ((u32)(a.y != 0) << 1)
                 | ((u32)(a.z != 0) << 2) | ((u32)(a.w != 0) << 3)
                 | ((u32)(b.x != 0) << 4) | ((u32)(b.y != 0) << 5)
                 | ((u32)(b.z != 0) << 6) | ((u32)(b.w != 0) << 7)
                 | ((u32)(c.x != 0) << 8) | ((u32)(c.y != 0) << 9)
                 | ((u32)(c.z != 0) << 10)| ((u32)(c.w != 0) << 11)
                 | ((u32)(d.x != 0) << 12)| ((u32)(d.y != 0) << 13)
                 | ((u32)(d.z != 0) << 14)| ((u32)(d.w != 0) << 15);
          } else {
            for (int i = 0; i < 16; ++i)
              if (s0 + sg + i < kS && ((const u32*)mraw)[base + i]) bits |= 1u << i;
          }
        } else if (mf == 0) {
          if (full) {
            const u8* m8 = (const u8*)mraw + base;
            uint2 a = *(const uint2*)(m8);
            uint2 b = *(const uint2*)(m8 + 8);
            bits = bytes_nz(a.x) | (bytes_nz(a.y) << 4)
                 | (bytes_nz(b.x) << 8) | (bytes_nz(b.y) << 12);
          } else {
            for (int i = 0; i < 16; ++i)
              if (s0 + sg + i < kS && ((const u8*)mraw)[base + i]) bits |= 1u << i;
          }
        } else {
          if (full) {
            const u16* m16 = (const u16*)mraw + base;
            uint4 a = *(const uint4*)(m16);
            uint4 b = *(const uint4*)(m16 + 8);
            bits = h2_nz(a.x) | (h2_nz(a.y) << 2) | (h2_nz(a.z) << 4) | (h2_nz(a.w) << 6)
                 | (h2_nz(b.x) << 8) | (h2_nz(b.y) << 10)
                 | (h2_nz(b.z) << 12) | (h2_nz(b.w) << 14);
          } else {
            for (int i = 0; i < 16; ++i)
              if (s0 + sg + i < kS && ((const u16*)mraw)[base + i]) bits |= 1u << i;
          }
        }
      }
      tb[row][tid & 3] = (u16)bits;
    }
    __syncthreads();
    const int w = tid >> 6, lane = tid & 63;
    for (int k = 0; k < 16; ++k) {
      const int ro = w * 16 + k;
      u32 b1 = (tb[ro][lane >> 4] >> (lane & 15)) & 1;
      u64 word = __ballot((int)b1);
      if (lane == 0) mkb[((size_t)n * kMW + (s0 >> 6)) * kTP + l0 + ro] = word;
      u32 b2 = (tb[lane][ro >> 4] >> (ro & 15)) & 1;
      u64 wordt = __ballot((int)b2);
      if (lane == 0) mkbt[((size_t)n * kMW + (l0 >> 6)) * kTP + s0 + ro] = wordt;
    }
  } else if (bx < NB_MASK + NB_CVT) {
    // x -> bf16, only needed for f32 inputs (bf16 inputs are read raw by proj)
    const u32 f2 = detect_f2_block((const u8*)x0, tid, dcnt);
    if (f2 == 1) {
      const int b2 = bx - NB_MASK;
      const void* X = (b2 >= 1500) ? x1 : x0;
      u16* B = (b2 >= 1500) ? xb1 : xb0;
      const int i = (b2 % 1500) * 256 + tid;
      float4 v = ((const float4*)X)[i];
      uint2 o;
      o.x = (u32)f2bf(v.x) | ((u32)f2bf(v.y) << 16);
      o.y = (u32)f2bf(v.z) | ((u32)f2bf(v.w) << 16);
      ((uint2*)B)[i] = o;
    }
  } else {
    const u32 f2 = detect_f2_block((const u8*)x0, tid, dcnt);
    const int b = bx - NB_MASK - NB_CVT, k = tid;
    if (b < 2 * kH) {
      int col = b;
      u16 v = (f2 == 0) ? ((const u16*)Wp)[(size_t)k * (2 * kH) + col]
                        : f2bf(((const float*)Wp)[(size_t)k * (2 * kH) + col]);
      WT[(size_t)col * kC + k] = v;
    } else {
      int col = b - 2 * kH;
      u16 v = (f2 == 0) ? ((const u16*)Wm)[(size_t)k * kC + col]
                        : f2bf(((const float*)Wm)[(size_t)k * kC + col]);
      WmT[(size_t)col * kH + k] = v;
    }
  }
}

// ---------------- K2: projection GEMM (64x64 tile, LDS-staged B) ----------------
// bf16 inputs: A-frags read RAW x (row-clamped). f32 inputs: read xb from prep.
__global__ __launch_bounds__(256) void k_proj(const void* __restrict__ x0,
                                              const void* __restrict__ x1,
                                              const u16* __restrict__ xb0,
                                              const u16* __restrict__ xb1,
                                              const u16* __restrict__ WT,
                                              const void* __restrict__ bias,
                                              u16* __restrict__ q0, u16* __restrict__ v0t,
                                              u16* __restrict__ q1, u16* __restrict__ v1t) {
  __shared__ int dcnt[8];
  const int tid = threadIdx.x;
  const u32 f2 = detect_f2_block((const u8*)x0, tid, dcnt);
  const int z = blockIdx.z;
  u16* Q = z ? q1 : q0;
  u16* V = z ? v1t : v0t;
  const int w = tid >> 6, lane = tid & 63;
  const int quad = lane >> 4, c16 = lane & 15;
  const int rb = blockIdx.x, cb = blockIdx.y;

  __align__(16) __shared__ u16 sB[64 * 264];
  {
    const u16* wp = WT + (size_t)(cb * 64 + (tid >> 2)) * kC + (tid & 3) * 64;
    u16* sp = sB + (tid >> 2) * 264 + (tid & 3) * 64;
#pragma unroll
    for (int i = 0; i < 8; ++i) *(uint4*)(sp + i * 8) = *(const uint4*)(wp + i * 8);
  }
  __syncthreads();

  int arow = rb * 64 + w * 16 + c16;              // 0..6015; clamp for raw reads
  if (arow > 2 * kL - 1) arow = 2 * kL - 1;
  const u16* ap;
  if (f2 == 0) ap = (const u16*)(z ? x1 : x0) + (size_t)arow * kC + quad * 8;
  else         ap = (z ? xb1 : xb0) + (size_t)arow * kC + quad * 8;

  f32x4 acc[4];
#pragma unroll
  for (int cg = 0; cg < 4; ++cg) acc[cg] = f32x4{0.f,0.f,0.f,0.f};
#pragma unroll
  for (int k0 = 0; k0 < 8; ++k0) {
    short8 a = *(const short8*)(ap + k0 * 32);
#pragma unroll
    for (int cg = 0; cg < 4; ++cg) {
      short8 b = *(const short8*)(sB + (cg * 16 + c16) * 264 + k0 * 32 + quad * 8);
      acc[cg] = mfma16(a, b, acc[cg]);
    }
  }

  const int row0 = rb * 64 + w * 16 + quad * 4;
  if (row0 < 2 * kL) {
    const int n = (row0 >= kL) ? 1 : 0;
    const int t0 = row0 - n * kL;
#pragma unroll
    for (int cg = 0; cg < 4; ++cg) {
      const int c = cb * 64 + cg * 16 + c16;
      float bb = (f2 == 0) ? bf2f(((const u16*)bias)[c]) : ((const float*)bias)[c];
      if (c < kH) {
        int ff = c >> 5, d = c & 31;
        u16* qp = Q + ((size_t)(n * kFC + ff) * kTP + t0) * kD + d;
#pragma unroll
        for (int r = 0; r < 4; ++r) qp[(size_t)r * kD] = f2bf((acc[cg][r] + bb) * kQSC);
      } else {
        int cc = c - kH;
        int ff = cc >> 5, d = cc & 31;
        uint2 o;
        o.x = (u32)f2bf(acc[cg][0] + bb) | ((u32)f2bf(acc[cg][1] + bb) << 16);
        o.y = (u32)f2bf(acc[cg][2] + bb) | ((u32)f2bf(acc[cg][3] + bb) << 16);
        *(uint2*)(V + ((size_t)(n * kFC + ff) * kD + d) * kTP + t0) = o;
      }
    }
  }
}

// ---------------- K3: bidirectional flash attention (two-pass, ones-MFMA sums) -----
__global__ __launch_bounds__(256) void k_flash(const u16* __restrict__ q0,
                                               const u16* __restrict__ q1,
                                               const u16* __restrict__ v0t,
                                               const u16* __restrict__ v1t,
                                               const u64* __restrict__ mkb,
                                               const u64* __restrict__ mkbt,
                                               u16* __restrict__ m0h, u16* __restrict__ m1h) {
  const int z = blockIdx.z;
  const u16* QA = z ? q1 : q0;
  const u16* QB = z ? q0 : q1;
  const u16* VT = z ? v0t : v1t;
  const u64* MB = z ? mkbt : mkb;
  u16* MO = z ? m1h : m0h;

  const int nf = blockIdx.y, n = nf >> 3, f = nf & 7;
  const int tid = threadIdx.x, w = tid >> 6, lane = tid & 63;
  const int quad = lane >> 4, c16 = lane & 15;

  __align__(16) __shared__ u16 sPall[4 * 4704];
  u16* sP = sPall + w * 4704;

  const u16* qa = QA + (size_t)(n * kFC + f) * kTP * kD;
  const u16* qb = QB + (size_t)(n * kFC + f) * kTP * kD;
  const u16* vt = VT + (size_t)(n * kFC + f) * kD * kTP;
  const u64* mb = MB + (size_t)n * kMW * kTP;

  const int l0 = blockIdx.x * 64;

  short8 af[4];
#pragma unroll
  for (int g = 0; g < 4; ++g) {
    const int ra = l0 + g * 16 + c16;
    af[g] = *(const short8*)(qa + (size_t)ra * kD + quad * 8);
  }
  short8 bones;
#pragma unroll
  for (int i = 0; i < 8; ++i) bones[i] = (short)0x3F80;

  f32x4 acc[4][2], accS[4];
#pragma unroll
  for (int g = 0; g < 4; ++g) {
    acc[g][0] = f32x4{0.f,0.f,0.f,0.f};
    acc[g][1] = f32x4{0.f,0.f,0.f,0.f};
    accS[g]   = f32x4{0.f,0.f,0.f,0.f};
  }

  u64 mword = mb[(size_t)w * kTP + l0 + lane];
  short8 aq0, aq1, aq2, aq3;
  {
    const u16* qbase = qb + (size_t)(w * 64 + c16) * kD + quad * 8;
    aq0 = *(const short8*)(qbase);
    aq1 = *(const short8*)(qbase + (size_t)16 * kD);
    aq2 = *(const short8*)(qbase + (size_t)32 * kD);
    aq3 = *(const short8*)(qbase + (size_t)48 * kD);
  }

#pragma unroll 1
  for (int jc = w; jc < 47; jc += 4) {
    const int j0 = jc * 64;
    const u16* vb = vt + (size_t)c16 * kTP + j0 + quad * 8;
    short8 bv00 = *(const short8*)(vb);
    short8 bv01 = *(const short8*)(vb + (size_t)16 * kTP);
    short8 bv10 = *(const short8*)(vb + 32);
    short8 bv11 = *(const short8*)(vb + (size_t)16 * kTP + 32);

    const u32 mlo = (u32)mword, mhi = (u32)(mword >> 32);

#pragma unroll
    for (int g = 0; g < 4; ++g) {
      const u32 lo = (u32)__shfl((int)mlo, g * 16 + c16);
      const u32 hi = (u32)__shfl((int)mhi, g * 16 + c16);
#pragma unroll
      for (int t = 0; t < 4; ++t) {
        short8 aq = (t == 0) ? aq0 : (t == 1) ? aq1 : (t == 2) ? aq2 : aq3;
        f32x4 zz = {0.f,0.f,0.f,0.f};
        f32x4 s = mfma16(aq, af[g], zz);         // C[s=quad*4+r][l=c16]
        const u32 hh = (t & 2) ? hi : lo;
        const int base = (t & 1) * 16 + quad * 4;
        float p0 = ((hh >> (base + 0)) & 1) ? __builtin_amdgcn_exp2f(s[0]) : 0.f;
        float p1 = ((hh >> (base + 1)) & 1) ? __builtin_amdgcn_exp2f(s[1]) : 0.f;
        float p2 = ((hh >> (base + 2)) & 1) ? __builtin_amdgcn_exp2f(s[2]) : 0.f;
        float p3 = ((hh >> (base + 3)) & 1) ? __builtin_amdgcn_exp2f(s[3]) : 0.f;
        uint2 pw; pw.x = pk2(p0, p1); pw.y = pk2(p2, p3);
        *(uint2*)(sP + (g * 16 + c16) * 72 + t * 16 + quad * 4) = pw;
      }
    }

    {
      int jn = jc + 4;
      const int jl = (jn < 47) ? jn : w;
      mword = mb[(size_t)jl * kTP + l0 + lane];
      const u16* qn = qb + (size_t)(jl * 64 + c16) * kD + quad * 8;
      aq0 = *(const short8*)(qn);
      aq1 = *(const short8*)(qn + (size_t)16 * kD);
      aq2 = *(const short8*)(qn + (size_t)32 * kD);
      aq3 = *(const short8*)(qn + (size_t)48 * kD);
    }

#pragma unroll
    for (int g = 0; g < 4; ++g) {
      short8 ap0 = *(const short8*)(sP + (g * 16 + c16) * 72 + quad * 8);
      short8 ap1 = *(const short8*)(sP + (g * 16 + c16) * 72 + 32 + quad * 8);
      acc[g][0] = mfma16(ap0, bv00, acc[g][0]);
      acc[g][1] = mfma16(ap0, bv01, acc[g][1]);
      accS[g]   = mfma16(ap0, bones, accS[g]);
      acc[g][0] = mfma16(ap1, bv10, acc[g][0]);
      acc[g][1] = mfma16(ap1, bv11, acc[g][1]);
      accS[g]   = mfma16(ap1, bones, accS[g]);
    }
  }

  __syncthreads();
  float* buf = (float*)sPall;
  if (w > 0) {
    const int rbase = (w - 1) * 3072;
#pragma unroll
    for (int g = 0; g < 4; ++g) {
#pragma unroll
      for (int r = 0; r < 4; ++r) {
        buf[rbase + (g * 12 + r)     * 64 + lane] = acc[g][0][r];
        buf[rbase + (g * 12 + 4 + r) * 64 + lane] = acc[g][1][r];
        buf[rbase + (g * 12 + 8 + r) * 64 + lane] = accS[g][r];
      }
    }
  }
  __syncthreads();
  if (w == 0) {
#pragma unroll
    for (int g = 0; g < 4; ++g) {
#pragma unroll
      for (int r = 0; r < 4; ++r) {
        float n0 = acc[g][0][r], n1 = acc[g][1][r], ls = accS[g][r];
#pragma unroll
        for (int ww = 0; ww < 3; ++ww) {
          n0 += buf[ww * 3072 + (g * 12 + r)     * 64 + lane];
          n1 += buf[ww * 3072 + (g * 12 + 4 + r) * 64 + lane];
          ls += buf[ww * 3072 + (g * 12 + 8 + r) * 64 + lane];
        }
        float rd = (ls > 0.f) ? (1.f / ls) : 0.f;
        int lrow = l0 + g * 16 + quad * 4 + r;
        if (lrow < kL) {
          size_t basep = ((size_t)n * kTP + lrow) * kH + f * kD;
          MO[basep + c16]      = f2bf(n0 * rd);
          MO[basep + 16 + c16] = f2bf(n1 * rd);
        }
      }
    }
  }
}

// ---------------- K5: merge GEMM (64x64 tile, LDS-staged B) + bias -> output -------
__global__ __launch_bounds__(256) void k_merge(const u16* __restrict__ m0h,
                                               const u16* __restrict__ m1h,
                                               const u16* __restrict__ WmT,
                                               const void* __restrict__ bias,
                                               const void* __restrict__ x0raw,
                                               void* __restrict__ out) {
  __shared__ int dcnt[8];
  const int tid = threadIdx.x;
  const u32 f2 = detect_f2_block((const u8*)x0raw, tid, dcnt);
  const int z = blockIdx.z;
  const u16* A = z ? m1h : m0h;
  const int w = tid >> 6, lane = tid & 63;
  const int quad = lane >> 4, c16 = lane & 15;
  const int rb = blockIdx.x, cb = blockIdx.y;

  __align__(16) __shared__ u16 sB[64 * 264];
  {
    const u16* wp = WmT + (size_t)(cb * 64 + (tid >> 2)) * kH + (tid & 3) * 64;
    u16* sp = sB + (tid >> 2) * 264 + (tid & 3) * 64;
#pragma unroll
    for (int i = 0; i < 8; ++i) *(uint4*)(sp + i * 8) = *(const uint4*)(wp + i * 8);
  }
  __syncthreads();

  const int arow = rb * 64 + w * 16 + c16;
  const u16* ap = A + (size_t)arow * kH + quad * 8;
  f32x4 acc[4];
#pragma unroll
  for (int cg = 0; cg < 4; ++cg) acc[cg] = f32x4{0.f,0.f,0.f,0.f};
#pragma unroll
  for (int k0 = 0; k0 < 8; ++k0) {
    short8 a = *(const short8*)(ap + k0 * 32);
#pragma unroll
    for (int cg = 0; cg < 4; ++cg) {
      short8 b = *(const short8*)(sB + (cg * 16 + c16) * 264 + k0 * 32 + quad * 8);
      acc[cg] = mfma16(a, b, acc[cg]);
    }
  }

  const int row0 = rb * 64 + w * 16 + quad * 4;
  const int n = (row0 >= kTP) ? 1 : 0;
  const int t0 = row0 - n * kTP;
  const size_t obase = (size_t)z * ((size_t)kNB * kL * kC);
#pragma unroll
  for (int cg = 0; cg < 4; ++cg) {
    const int c = cb * 64 + cg * 16 + c16;
    float bb = (f2 == 0) ? bf2f(((const u16*)bias)[c]) : ((const float*)bias)[c];
#pragma unroll
    for (int r = 0; r < 4; ++r) {
      const int t = t0 + r;
      if (t < kL) {
        size_t oi = obase + ((size_t)n * kL + t) * kC + c;
        float v = acc[cg][r] + bb;
        if (f2 == 0) ((u16*)out)[oi] = f2bf(v);
        else         ((float*)out)[oi] = v;
      }
    }
  }
}

// ---------------- host ----------------
extern "C" void kernel_launch(void* const* d_in, const int* in_sizes, int n_in,
                              void* d_out, int out_size, void* d_ws, size_t ws_size,
                              hipStream_t stream) {
  (void)in_sizes; (void)n_in; (void)out_size; (void)ws_size;
  u8* ws = (u8*)d_ws;
  u16* q0  = (u16*)(ws + OFF_Q0);
  u16* q1  = (u16*)(ws + OFF_Q1);
  u16* v0t = (u16*)(ws + OFF_V0);
  u16* v1t = (u16*)(ws + OFF_V1);
  u16* m0h = (u16*)(ws + OFF_M0);
  u16* m1h = (u16*)(ws + OFF_M1);
  u16* WT  = (u16*)(ws + OFF_WT);
  u16* WmT = (u16*)(ws + OFF_WM);
  u16* xb0 = (u16*)(ws + OFF_X0);
  u16* xb1 = (u16*)(ws + OFF_X1);
  u64* mkb  = (u64*)(ws + OFF_MKB);
  u64* mkbt = (u64*)(ws + OFF_MKBT);

  const void* x0 = d_in[0];
  const void* x1 = d_in[1];
  const void* mraw = d_in[2];
  const void* Wp = d_in[3];
  const void* bp = d_in[4];
  const void* Wm = d_in[5];
  const void* bm = d_in[6];

  k_prep<<<dim3(NB_MASK + NB_CVT + NB_WT), 256, 0, stream>>>(
      mraw, x0, x1, Wp, Wm, mkb, mkbt, xb0, xb1, WT, WmT);
  k_proj<<<dim3(94, 8, 2), 256, 0, stream>>>(x0, x1, xb0, xb1, WT, bp,
                                             q0, v0t, q1, v1t);
  k_flash<<<dim3(47, 16, 2), 256, 0, stream>>>(q0, q1, v0t, v1t, mkb, mkbt, m0h, m1h);
  k_merge<<<dim3(94, 4, 2), 256, 0, stream>>>(m0h, m1h, WmT, bm, x0, d_out);
}